// Round 1
// baseline (1149.240 us; speedup 1.0000x reference)
//
#include <hip/hip_runtime.h>

// AttentionDecoder: B=65536, T=10, E=64, H=64, D=5
// Strategy: one wave owns 16 batch rows end-to-end (no inter-wave sync in the
// step loop). bf16 MFMA 16x16x32 for: enc_proj (pre-loop), xf/xo projections
// (pre-loop; context is only used linearly so it is never materialized),
// attn matvec and LSTM gates matvec (per step). enc_proj + xf/xo live in
// registers in MFMA C-layout (T-major tiling => lane-aligned with the attn
// GEMM output). tanh/sigmoid via v_exp_f32 with log2e folded into weights.

#define DEVFN __device__ __forceinline__

typedef __attribute__((ext_vector_type(8))) short short8;
typedef __attribute__((ext_vector_type(4))) float f32x4;
typedef __attribute__((ext_vector_type(4))) int int4v;

DEVFN unsigned bfr(float f) {  // f32 -> bf16 bits, round-to-nearest-even
  unsigned u = __float_as_uint(f);
  return (u + 0x7fffu + ((u >> 16) & 1u)) >> 16;
}
DEVFN unsigned pk2(float lo, float hi) { return bfr(lo) | (bfr(hi) << 16); }
DEVFN float ulo(unsigned p) { return __uint_as_float(p << 16); }
DEVFN float uhi(unsigned p) { return __uint_as_float(p & 0xffff0000u); }

// wave-internal LDS fence: cross-lane data exchange within one wave needs the
// ds_writes drained before dependent ds_reads; no s_barrier required.
DEVFN void lds_fence() {
  __builtin_amdgcn_wave_barrier();
  asm volatile("s_waitcnt lgkmcnt(0)" ::: "memory");
  __builtin_amdgcn_wave_barrier();
}

#define MFMA(a, b, c) __builtin_amdgcn_mfma_f32_16x16x32_bf16((a), (b), (c), 0, 0, 0)

// ---- LDS layout (bytes) ----
#define OFF_BHCT 0           // [64][136] bf16: W1_hc rows (e) x (j=0..127), *2log2e
#define OFF_BHHT 17408       // [256][72] bf16: W_hh rows (i) x (h), gate-scaled
#define OFF_BENC 54272       // [64][72]  bf16: W1_enc rows (e) x (d), *2log2e
#define OFF_BPRJ 63488       // [16][72]  bf16: rows n<5: fc_w[n][0:64]; n in 8..12: fco_w[n-8][64:128]
#define OFF_WIH  65792       // [5][256]  f32 : W_ih^T, gate-scaled
#define OFF_FCO  70912       // [5][64]   f32 : fco_w[:, :64]
#define OFF_PW   72192       // per-wave regions
#define PWSZ     8064        //   +0: scratch [16][136] bf16 (x-tile then hc staging)
                             //   +4352: ytilde [16][8] f32
                             //   +4864: y_hist [16][50] f32
#define SMEM_BYTES (OFF_PW + 8 * PWSZ)  // 136704

__global__ __launch_bounds__(512, 2) void attn_dec(
    const float* __restrict__ xg,   const float* __restrict__ yg,
    const float* __restrict__ h0,   const float* __restrict__ c0,
    const float* __restrict__ w1,   const float* __restrict__ b1g,
    const float* __restrict__ w2g,  const float* __restrict__ b2g,
    const float* __restrict__ wihg, const float* __restrict__ whhg,
    const float* __restrict__ bihg, const float* __restrict__ bhhg,
    const float* __restrict__ fcwg, const float* __restrict__ fcbg,
    const float* __restrict__ fcowg, const float* __restrict__ fcobg,
    float* __restrict__ outg) {
  (void)b2g;  // attn_b2 is constant across t -> softmax-invariant, dropped
  extern __shared__ char smem[];
  unsigned short* BHCT = (unsigned short*)(smem + OFF_BHCT);
  unsigned short* BHHT = (unsigned short*)(smem + OFF_BHHT);
  unsigned short* BENC = (unsigned short*)(smem + OFF_BENC);
  unsigned short* BPRJ = (unsigned short*)(smem + OFF_BPRJ);
  float* WIHT = (float*)(smem + OFF_WIH);
  float* FCOL = (float*)(smem + OFF_FCO);

  const int tid = threadIdx.x;
  const int wave = tid >> 6, lane = tid & 63;
  const int q = lane >> 4, m = lane & 15;
  const int rb = blockIdx.x * 128 + wave * 16;  // global batch-row base of this wave

  const float S2  = 2.88539008177792681f;   // 2*log2(e)
  const float NL  = -1.44269504088896341f;  // -log2(e)
  const float L2E = 1.44269504088896341f;

  unsigned short* SCR = (unsigned short*)(smem + OFF_PW + wave * PWSZ);
  float* YTL = (float*)(smem + OFF_PW + wave * PWSZ + 4352);
  float* YH  = (float*)(smem + OFF_PW + wave * PWSZ + 4864);

  // ---------- cooperative shared-weight staging ----------
  for (int idx = tid; idx < 64 * 192; idx += 512) {
    int e = idx / 192, j = idx - e * 192;
    float v = w1[idx] * S2;  // tanh arg pre-scaled by 2*log2(e)
    if (j < 128) BHCT[e * 136 + j] = (unsigned short)bfr(v);
    else         BENC[e * 72 + (j - 128)] = (unsigned short)bfr(v);
  }
  for (int idx = tid; idx < 256 * 64; idx += 512) {
    int i = idx >> 6;
    float s = (i >= 128 && i < 192) ? S2 : NL;  // g-gate: tanh scale; i,f,o: -log2e for sigmoid
    BHHT[i * 72 + (idx & 63)] = (unsigned short)bfr(whhg[idx] * s);
  }
  for (int idx = tid; idx < 16 * 64; idx += 512) {
    int n = idx >> 6, d = idx & 63;
    float v = 0.f;
    if (n < 5) v = fcwg[n * 69 + d];
    else if (n >= 8 && n < 13) v = fcowg[(n - 8) * 128 + 64 + d];
    BPRJ[n * 72 + d] = (unsigned short)bfr(v);
  }
  for (int idx = tid; idx < 5 * 256; idx += 512) {
    int d = idx >> 8, i = idx & 255;
    float s = (i >= 128 && i < 192) ? S2 : NL;
    WIHT[idx] = wihg[i * 5 + d] * s;
  }
  for (int idx = tid; idx < 5 * 64; idx += 512) {
    int d = idx >> 6, h = idx & 63;
    FCOL[idx] = fcowg[d * 128 + h];
  }
  __syncthreads();

  // ---------- per-wave y_history tile ----------
  for (int idx = lane; idx < 800; idx += 64) {
    int r = idx / 50, c = idx - r * 50;
    YH[idx] = yg[(size_t)(rb + r) * 50 + c];
  }

  // ---------- per-lane constants ----------
  float b1e[4], w2e[4];
#pragma unroll
  for (int et = 0; et < 4; ++et) {
    b1e[et] = b1g[et * 16 + m] * S2;
    w2e[et] = w2g[et * 16 + m];
  }
  float bgc[16];
#pragma unroll
  for (int g = 0; g < 4; ++g)
#pragma unroll
    for (int hg = 0; hg < 4; ++hg) {
      int i = g * 64 + hg * 16 + m;
      float s = (g == 2) ? S2 : NL;
      bgc[g * 4 + hg] = (bihg[i] + bhhg[i]) * s;
    }
  const int mc = (m < 5) ? m : 4;
  float fcwy[5];
#pragma unroll
  for (int j = 0; j < 5; ++j) fcwy[j] = fcwg[mc * 69 + 64 + j];
  const float fcbv = fcbg[mc];
  const float fcobv = fcobg[mc];

  // ---------- pre-loop: enc_proj (ep) and xf/xo projections into registers ----------
  // T-major tiling: rt-tile t holds rows r=0..15 => C-layout rows == batch rows,
  // identical lane mapping to the per-step attn GEMM output.
  unsigned ep[10][4][2];  // [t][e-tile][row-pair] packed bf16 (scaled by 2log2e)
  unsigned xfo[10][2];    // [t][row-pair]: col m<5 -> xf_d, col 8..12 -> xo_(m-8)
  {
    const int rl = lane >> 2, cc = lane & 3;
#pragma unroll
    for (int t = 0; t < 10; ++t) {
      lds_fence();  // WAR vs previous iteration's A-frag reads
      const float4* xp = (const float4*)(xg + (size_t)(rb + rl) * 640 + t * 64 + cc * 16);
      float4 v0 = xp[0], v1 = xp[1], v2 = xp[2], v3 = xp[3];
      int4v d0, d1;
      d0.x = (int)pk2(v0.x, v0.y); d0.y = (int)pk2(v0.z, v0.w);
      d0.z = (int)pk2(v1.x, v1.y); d0.w = (int)pk2(v1.z, v1.w);
      d1.x = (int)pk2(v2.x, v2.y); d1.y = (int)pk2(v2.z, v2.w);
      d1.z = (int)pk2(v3.x, v3.y); d1.w = (int)pk2(v3.z, v3.w);
      *(int4v*)(SCR + rl * 72 + cc * 16) = d0;
      *(int4v*)(SCR + rl * 72 + cc * 16 + 8) = d1;
      lds_fence();
      short8 a0 = *(const short8*)(SCR + m * 72 + q * 8);
      short8 a1 = *(const short8*)(SCR + m * 72 + 32 + q * 8);
#pragma unroll
      for (int et = 0; et < 4; ++et) {
        f32x4 acc = {0.f, 0.f, 0.f, 0.f};
        const unsigned short* bp = BENC + (et * 16 + m) * 72 + q * 8;
        acc = MFMA(a0, *(const short8*)bp, acc);
        acc = MFMA(a1, *(const short8*)(bp + 32), acc);
        ep[t][et][0] = pk2(acc[0], acc[1]);
        ep[t][et][1] = pk2(acc[2], acc[3]);
      }
      {
        f32x4 acc = {0.f, 0.f, 0.f, 0.f};
        const unsigned short* bp = BPRJ + m * 72 + q * 8;
        acc = MFMA(a0, *(const short8*)bp, acc);
        acc = MFMA(a1, *(const short8*)(bp + 32), acc);
        xfo[t][0] = pk2(acc[0], acc[1]);
        xfo[t][1] = pk2(acc[2], acc[3]);
      }
    }
  }

  // ---------- init state: ct in f32 regs, [ht|ct] bf16 staging in SCR ----------
  float ctr[16];  // [hg*4 + r]
  lds_fence();
#pragma unroll
  for (int hg = 0; hg < 4; ++hg)
#pragma unroll
    for (int r = 0; r < 4; ++r) {
      int row = q * 4 + r, h = hg * 16 + m;
      float hv = h0[(size_t)(rb + row) * 64 + h];
      float cv = c0[(size_t)(rb + row) * 64 + h];
      ctr[hg * 4 + r] = cv;
      SCR[row * 136 + h] = (unsigned short)bfr(hv);
      SCR[row * 136 + 64 + h] = (unsigned short)bfr(cv);
    }
  lds_fence();

  // ---------- step loop (no inter-wave synchronization) ----------
  float yc[4] = {0.f, 0.f, 0.f, 0.f};
#pragma unroll 1
  for (int s = 0; s < 10; ++s) {
    // A) attn matvec: attn_lin = hc @ W1_hc^T (pre-scaled), += b1
    short8 a0 = *(const short8*)(SCR + m * 136 + q * 8);
    short8 a1 = *(const short8*)(SCR + m * 136 + 32 + q * 8);
    short8 a2 = *(const short8*)(SCR + m * 136 + 64 + q * 8);
    short8 a3 = *(const short8*)(SCR + m * 136 + 96 + q * 8);
    float ac[4][4];
#pragma unroll
    for (int et = 0; et < 4; ++et) {
      f32x4 acc = {0.f, 0.f, 0.f, 0.f};
      const unsigned short* bp = BHCT + (et * 16 + m) * 136 + q * 8;
      acc = MFMA(a0, *(const short8*)bp, acc);
      acc = MFMA(a1, *(const short8*)(bp + 32), acc);
      acc = MFMA(a2, *(const short8*)(bp + 64), acc);
      acc = MFMA(a3, *(const short8*)(bp + 96), acc);
      ac[et][0] = acc[0] + b1e[et];
      ac[et][1] = acc[1] + b1e[et];
      ac[et][2] = acc[2] + b1e[et];
      ac[et][3] = acc[3] + b1e[et];
    }
    // B) scores[r][t] = sum_e w2[e] * tanh(pre); reduce over e (regs + 16-lane xor)
    float sc[4][10];
#pragma unroll
    for (int t = 0; t < 10; ++t) {
      float p0 = 0.f, p1 = 0.f, p2 = 0.f, p3 = 0.f;
#pragma unroll
      for (int et = 0; et < 4; ++et) {
        unsigned plo = ep[t][et][0], phi = ep[t][et][1];
        float x0 = ac[et][0] + ulo(plo);
        float x1 = ac[et][1] + uhi(plo);
        float x2 = ac[et][2] + ulo(phi);
        float x3 = ac[et][3] + uhi(phi);
        float e0 = __builtin_amdgcn_exp2f(x0);
        float e1 = __builtin_amdgcn_exp2f(x1);
        float e2 = __builtin_amdgcn_exp2f(x2);
        float e3 = __builtin_amdgcn_exp2f(x3);
        float w = w2e[et];
        p0 += w * ((e0 - 1.f) * __builtin_amdgcn_rcpf(e0 + 1.f));
        p1 += w * ((e1 - 1.f) * __builtin_amdgcn_rcpf(e1 + 1.f));
        p2 += w * ((e2 - 1.f) * __builtin_amdgcn_rcpf(e2 + 1.f));
        p3 += w * ((e3 - 1.f) * __builtin_amdgcn_rcpf(e3 + 1.f));
      }
      p0 += __shfl_xor(p0, 1); p0 += __shfl_xor(p0, 2); p0 += __shfl_xor(p0, 4); p0 += __shfl_xor(p0, 8);
      p1 += __shfl_xor(p1, 1); p1 += __shfl_xor(p1, 2); p1 += __shfl_xor(p1, 4); p1 += __shfl_xor(p1, 8);
      p2 += __shfl_xor(p2, 1); p2 += __shfl_xor(p2, 2); p2 += __shfl_xor(p2, 4); p2 += __shfl_xor(p2, 8);
      p3 += __shfl_xor(p3, 1); p3 += __shfl_xor(p3, 2); p3 += __shfl_xor(p3, 4); p3 += __shfl_xor(p3, 8);
      sc[0][t] = p0; sc[1][t] = p1; sc[2][t] = p2; sc[3][t] = p3;
    }
    // C/D) softmax over t + contract alpha with xf (and xo, kept for final step)
#pragma unroll
    for (int r = 0; r < 4; ++r) {
      float mx = sc[r][0];
#pragma unroll
      for (int t = 1; t < 10; ++t) mx = fmaxf(mx, sc[r][t]);
      float sum = 0.f, al[10];
#pragma unroll
      for (int t = 0; t < 10; ++t) { al[t] = __builtin_amdgcn_exp2f((sc[r][t] - mx) * L2E); sum += al[t]; }
      float rs = __builtin_amdgcn_rcpf(sum);
      float accv = 0.f;
#pragma unroll
      for (int t = 0; t < 10; ++t) {
        unsigned p = xfo[t][r >> 1];
        accv += al[t] * ((r & 1) ? uhi(p) : ulo(p));
      }
      yc[r] = accv * rs;
    }
    // E) y_tilde[row][d] (lanes m<5)
#pragma unroll
    for (int r = 0; r < 4; ++r) {
      int row = q * 4 + r;
      float v = yc[r] + fcbv;
#pragma unroll
      for (int j = 0; j < 5; ++j) v += fcwy[j] * YH[row * 50 + s * 5 + j];
      if (m < 5) YTL[row * 8 + m] = v;
    }
    lds_fence();
    float ytv[4][5];
#pragma unroll
    for (int r = 0; r < 4; ++r)
#pragma unroll
      for (int j = 0; j < 5; ++j) ytv[r][j] = YTL[(q * 4 + r) * 8 + j];
    // F/G) gates GEMM (+W_ih*y_tilde + bias) and LSTM update, 2 h-groups at a time
#pragma unroll
    for (int hgp = 0; hgp < 2; ++hgp) {
      float ga[2][4][4];
#pragma unroll
      for (int hh = 0; hh < 2; ++hh) {
        int hg = hgp * 2 + hh;
#pragma unroll
        for (int g = 0; g < 4; ++g) {
          int n = g * 64 + hg * 16 + m;
          f32x4 acc = {0.f, 0.f, 0.f, 0.f};
          const unsigned short* bp = BHHT + n * 72 + q * 8;
          acc = MFMA(a0, *(const short8*)bp, acc);
          acc = MFMA(a1, *(const short8*)(bp + 32), acc);
          float wv0 = WIHT[n], wv1 = WIHT[256 + n], wv2 = WIHT[512 + n],
                wv3 = WIHT[768 + n], wv4 = WIHT[1024 + n];
#pragma unroll
          for (int r = 0; r < 4; ++r) {
            float gv = acc[r] + bgc[g * 4 + hg];
            gv += wv0 * ytv[r][0] + wv1 * ytv[r][1] + wv2 * ytv[r][2] +
                  wv3 * ytv[r][3] + wv4 * ytv[r][4];
            ga[hh][g][r] = gv;
          }
        }
      }
#pragma unroll
      for (int hh = 0; hh < 2; ++hh) {
        int hg = hgp * 2 + hh;
#pragma unroll
        for (int r = 0; r < 4; ++r) {
          float iv = __builtin_amdgcn_rcpf(1.f + __builtin_amdgcn_exp2f(ga[hh][0][r]));
          float fv = __builtin_amdgcn_rcpf(1.f + __builtin_amdgcn_exp2f(ga[hh][1][r]));
          float Eg = __builtin_amdgcn_exp2f(ga[hh][2][r]);
          float gv = (Eg - 1.f) * __builtin_amdgcn_rcpf(Eg + 1.f);
          float ov = __builtin_amdgcn_rcpf(1.f + __builtin_amdgcn_exp2f(ga[hh][3][r]));
          float c = fv * ctr[hg * 4 + r] + iv * gv;
          ctr[hg * 4 + r] = c;
          float Ec = __builtin_amdgcn_exp2f(c * S2);
          float th = (Ec - 1.f) * __builtin_amdgcn_rcpf(Ec + 1.f);
          float hv = ov * th;
          int row = q * 4 + r, h = hg * 16 + m;
          SCR[row * 136 + h] = (unsigned short)bfr(hv);
          SCR[row * 136 + 64 + h] = (unsigned short)bfr(c);
        }
      }
    }
    lds_fence();
  }

  // ---------- output: out = [ht, context] @ fco_w^T + fco_b ----------
#pragma unroll
  for (int r = 0; r < 4; ++r) {
    int row = q * 4 + r;
    // context part: lanes 8..12 hold sum_t alpha_9[t]*xo[t][d]; shuffle to d-lanes
    float sum = fcobv + __shfl(yc[r], (lane & 48) + 8 + mc);
#pragma unroll
    for (int hq = 0; hq < 8; ++hq) {
      int4v hv = *(const int4v*)(SCR + row * 136 + hq * 8);
      const float* fp = FCOL + mc * 64 + hq * 8;
      sum += fp[0] * ulo((unsigned)hv.x) + fp[1] * uhi((unsigned)hv.x)
           + fp[2] * ulo((unsigned)hv.y) + fp[3] * uhi((unsigned)hv.y)
           + fp[4] * ulo((unsigned)hv.z) + fp[5] * uhi((unsigned)hv.z)
           + fp[6] * ulo((unsigned)hv.w) + fp[7] * uhi((unsigned)hv.w);
    }
    if (m < 5) outg[(size_t)(rb + row) * 5 + m] = sum;
  }
}

extern "C" void kernel_launch(void* const* d_in, const int* in_sizes, int n_in,
                              void* d_out, int out_size, void* d_ws, size_t ws_size,
                              hipStream_t stream) {
  (void)in_sizes; (void)n_in; (void)d_ws; (void)ws_size; (void)out_size;
  hipFuncSetAttribute((const void*)attn_dec,
                      hipFuncAttributeMaxDynamicSharedMemorySize, SMEM_BYTES);
  attn_dec<<<dim3(512), dim3(512), SMEM_BYTES, stream>>>(
      (const float*)d_in[0], (const float*)d_in[1], (const float*)d_in[2],
      (const float*)d_in[3], (const float*)d_in[4], (const float*)d_in[5],
      (const float*)d_in[6], (const float*)d_in[7], (const float*)d_in[8],
      (const float*)d_in[9], (const float*)d_in[10], (const float*)d_in[11],
      (const float*)d_in[12], (const float*)d_in[13], (const float*)d_in[14],
      (const float*)d_in[15], (float*)d_out);
}

// Round 3
// 558.516 us; speedup vs baseline: 2.0577x; 2.0577x over previous
//
#include <hip/hip_runtime.h>

// AttentionDecoder: B=65536, T=10, E=64, H=64, D=5
// One wave owns 16 batch rows end-to-end; no inter-wave sync in the step loop.
// R2/R3 changes vs R1 (spill fix): ep/xfo pinned in AGPRs via v_accvgpr asm
// (R1 spilled ~620MB to scratch: WRITE_SIZE 179MB vs 1.3MB output);
// online no-max softmax (scores bounded by sum|w2|<=8 -> f32-safe) kills
// sc[40]+al[10]; DPP allreduce replaces ds_swizzle butterflies (LGKM->VALU);
// y_tilde enters gates via a 3rd MFMA (zero-padded W_ih panel) instead of
// 320 scalar FMAs; biases folded into MFMA acc init.
// R3: dpp ctrl as template parameter (builtin requires ICE at call site).

#define DEVFN __device__ __forceinline__

typedef __attribute__((ext_vector_type(8))) short short8;
typedef __attribute__((ext_vector_type(4))) float f32x4;
typedef __attribute__((ext_vector_type(4))) int int4v;

DEVFN unsigned bfr(float f) {  // f32 -> bf16 bits, round-to-nearest-even
  unsigned u = __float_as_uint(f);
  return (u + 0x7fffu + ((u >> 16) & 1u)) >> 16;
}
DEVFN unsigned pk2(float lo, float hi) { return bfr(lo) | (bfr(hi) << 16); }
DEVFN float ulo(unsigned p) { return __uint_as_float(p << 16); }
DEVFN float uhi(unsigned p) { return __uint_as_float(p & 0xffff0000u); }

// AGPR pinning: cold per-lane state lives in the otherwise-idle AGPR half.
DEVFN void awr(unsigned &a, unsigned v) {
  asm("v_accvgpr_write_b32 %0, %1" : "=a"(a) : "v"(v));
}
DEVFN unsigned ard(const unsigned &a) {
  unsigned v;
  asm("v_accvgpr_read_b32 %0, %1" : "=v"(v) : "a"(a));
  return v;
}

// 16-lane all-reduce sum, pure VALU (DPP), no LGKM traffic.
template <int CTRL>
DEVFN float dppadd(float v) {
  int t = __builtin_amdgcn_update_dpp(0, __float_as_int(v), CTRL, 0xf, 0xf, true);
  return v + __int_as_float(t);
}
DEVFN float sum16(float v) {
  v = dppadd<0xB1>(v);   // quad_perm(1,0,3,2)
  v = dppadd<0x4E>(v);   // quad_perm(2,3,0,1)
  v = dppadd<0x124>(v);  // row_ror:4
  v = dppadd<0x128>(v);  // row_ror:8
  return v;
}

// wave-internal LDS fence (cross-lane exchange within one wave).
DEVFN void lds_fence() {
  __builtin_amdgcn_wave_barrier();
  asm volatile("s_waitcnt lgkmcnt(0)" ::: "memory");
  __builtin_amdgcn_wave_barrier();
}

#define MFMA(a, b, c) __builtin_amdgcn_mfma_f32_16x16x32_bf16((a), (b), (c), 0, 0, 0)

// ---- LDS layout (bytes) ----
#define OFF_BHCT 0       // [64][136] bf16: W1_hc rows (e) x (j=0..127), *2log2e
#define OFF_BHHT 17408   // [256][72] bf16: W_hh rows (i) x (h), gate-scaled
#define OFF_BENC 54272   // [64][72]  bf16: W1_enc rows (e) x (d), *2log2e
#define OFF_BPRJ 63488   // [16][72]  bf16: n<5: fc_w[n][0:64]; n in 8..12: fco_w[n-8][64:128]
#define OFF_BIH  65792   // [256][40] bf16: W_ih gate-scaled in cols 0..4, zeros 5..31
#define OFF_BGC  86272   // [256]     f32 : (b_ih+b_hh) gate-scaled
#define OFF_FCO  87296   // [5][64]   f32 : fco_w[:, :64]
#define OFF_PW   88576   // per-wave regions
#define PWSZ     8832    //   +0: SCR [16][136] bf16 (x-tile staging, then hc)
                         //   +4352: YH [16][50] f32
                         //   +7552: YTA [16][40] bf16 (y_tilde in A-layout)
#define SMEM_BYTES (OFF_PW + 8 * PWSZ)  // 159232

__global__ __launch_bounds__(512, 2) void attn_dec(
    const float* __restrict__ xg,   const float* __restrict__ yg,
    const float* __restrict__ h0,   const float* __restrict__ c0,
    const float* __restrict__ w1,   const float* __restrict__ b1g,
    const float* __restrict__ w2g,  const float* __restrict__ b2g,
    const float* __restrict__ wihg, const float* __restrict__ whhg,
    const float* __restrict__ bihg, const float* __restrict__ bhhg,
    const float* __restrict__ fcwg, const float* __restrict__ fcbg,
    const float* __restrict__ fcowg, const float* __restrict__ fcobg,
    float* __restrict__ outg) {
  (void)b2g;  // constant across t -> softmax-invariant
  extern __shared__ char smem[];
  unsigned short* BHCT = (unsigned short*)(smem + OFF_BHCT);
  unsigned short* BHHT = (unsigned short*)(smem + OFF_BHHT);
  unsigned short* BENC = (unsigned short*)(smem + OFF_BENC);
  unsigned short* BPRJ = (unsigned short*)(smem + OFF_BPRJ);
  unsigned short* BIH  = (unsigned short*)(smem + OFF_BIH);
  float* BGC  = (float*)(smem + OFF_BGC);
  float* FCOL = (float*)(smem + OFF_FCO);

  const int tid = threadIdx.x;
  const int wave = tid >> 6, lane = tid & 63;
  const int q = lane >> 4, m = lane & 15;
  const int rb = blockIdx.x * 128 + wave * 16;

  const float S2  = 2.88539008177792681f;   // 2*log2(e)
  const float NL  = -1.44269504088896341f;  // -log2(e)
  const float L2E = 1.44269504088896341f;

  unsigned short* SCR = (unsigned short*)(smem + OFF_PW + wave * PWSZ);
  float* YH = (float*)(smem + OFF_PW + wave * PWSZ + 4352);
  unsigned short* YTA = (unsigned short*)(smem + OFF_PW + wave * PWSZ + 7552);

  // ---------- cooperative shared-weight staging ----------
  for (int idx = tid; idx < 64 * 192; idx += 512) {
    int e = idx / 192, j = idx - e * 192;
    float v = w1[idx] * S2;
    if (j < 128) BHCT[e * 136 + j] = (unsigned short)bfr(v);
    else         BENC[e * 72 + (j - 128)] = (unsigned short)bfr(v);
  }
  for (int idx = tid; idx < 256 * 64; idx += 512) {
    int i = idx >> 6;
    float s = (i >= 128 && i < 192) ? S2 : NL;
    BHHT[i * 72 + (idx & 63)] = (unsigned short)bfr(whhg[idx] * s);
  }
  for (int idx = tid; idx < 16 * 64; idx += 512) {
    int n = idx >> 6, d = idx & 63;
    float v = 0.f;
    if (n < 5) v = fcwg[n * 69 + d];
    else if (n >= 8 && n < 13) v = fcowg[(n - 8) * 128 + 64 + d];
    BPRJ[n * 72 + d] = (unsigned short)bfr(v);
  }
  for (int idx = tid; idx < 256 * 32; idx += 512) {
    int n = idx >> 5, k = idx & 31;
    float s = (n >= 128 && n < 192) ? S2 : NL;
    float v = (k < 5) ? wihg[n * 5 + k] * s : 0.f;
    BIH[n * 40 + k] = (unsigned short)bfr(v);
  }
  for (int idx = tid; idx < 256; idx += 512) {
    float s = (idx >= 128 && idx < 192) ? S2 : NL;
    BGC[idx] = (bihg[idx] + bhhg[idx]) * s;
  }
  for (int idx = tid; idx < 5 * 64; idx += 512) {
    int d = idx >> 6, h = idx & 63;
    FCOL[idx] = fcowg[d * 128 + h];
  }
  __syncthreads();

  // ---------- per-wave: YH tile + YTA zero (pad cols of YTA stay unread) ----------
  for (int idx = lane; idx < 800; idx += 64) {
    int r = idx / 50, c = idx - r * 50;
    YH[idx] = yg[(size_t)(rb + r) * 50 + c];
  }
  for (int idx = lane; idx < 512; idx += 64)
    YTA[(idx >> 5) * 40 + (idx & 31)] = 0;

  // ---------- per-lane constants ----------
  float b1e[4], w2e[4];
#pragma unroll
  for (int et = 0; et < 4; ++et) {
    b1e[et] = b1g[et * 16 + m] * S2;
    w2e[et] = w2g[et * 16 + m] * L2E;  // fold softmax log2e into score
  }
  const int mc = (m < 5) ? m : 4;
  float fcwy[5];
#pragma unroll
  for (int j = 0; j < 5; ++j) fcwy[j] = fcwg[mc * 69 + 64 + j];
  const float fcbv = fcbg[mc];
  const float fcobv = fcobg[mc];

  // ---------- pre-loop: enc_proj + xf/xo projections -> AGPRs ----------
  unsigned ep[10][4][2];  // [t][e-tile][row-pair] packed bf16, *2log2e  (AGPR)
  unsigned xfo[10][2];    // [t][row-pair]: col m<5 -> xf_d; col 8..12 -> xo  (AGPR)
  {
    const int rl = lane >> 2, cc = lane & 3;
#pragma unroll
    for (int t = 0; t < 10; ++t) {
      lds_fence();  // WAR vs previous iteration's A-frag reads
      const float4* xp = (const float4*)(xg + (size_t)(rb + rl) * 640 + t * 64 + cc * 16);
      float4 v0 = xp[0], v1 = xp[1], v2 = xp[2], v3 = xp[3];
      int4v d0, d1;
      d0.x = (int)pk2(v0.x, v0.y); d0.y = (int)pk2(v0.z, v0.w);
      d0.z = (int)pk2(v1.x, v1.y); d0.w = (int)pk2(v1.z, v1.w);
      d1.x = (int)pk2(v2.x, v2.y); d1.y = (int)pk2(v2.z, v2.w);
      d1.z = (int)pk2(v3.x, v3.y); d1.w = (int)pk2(v3.z, v3.w);
      *(int4v*)(SCR + rl * 72 + cc * 16) = d0;
      *(int4v*)(SCR + rl * 72 + cc * 16 + 8) = d1;
      lds_fence();
      short8 xa0 = *(const short8*)(SCR + m * 72 + q * 8);
      short8 xa1 = *(const short8*)(SCR + m * 72 + 32 + q * 8);
#pragma unroll
      for (int et = 0; et < 4; ++et) {
        f32x4 acc = {0.f, 0.f, 0.f, 0.f};
        const unsigned short* bp = BENC + (et * 16 + m) * 72 + q * 8;
        acc = MFMA(xa0, *(const short8*)bp, acc);
        acc = MFMA(xa1, *(const short8*)(bp + 32), acc);
        awr(ep[t][et][0], pk2(acc[0], acc[1]));
        awr(ep[t][et][1], pk2(acc[2], acc[3]));
      }
      {
        f32x4 acc = {0.f, 0.f, 0.f, 0.f};
        const unsigned short* bp = BPRJ + m * 72 + q * 8;
        acc = MFMA(xa0, *(const short8*)bp, acc);
        acc = MFMA(xa1, *(const short8*)(bp + 32), acc);
        awr(xfo[t][0], pk2(acc[0], acc[1]));
        awr(xfo[t][1], pk2(acc[2], acc[3]));
      }
    }
  }

  // ---------- init state: ct f32 regs; [ht|ct] bf16 in SCR ----------
  float ctr[16];  // [hg*4 + r]
  lds_fence();
#pragma unroll
  for (int hg = 0; hg < 4; ++hg)
#pragma unroll
    for (int r = 0; r < 4; ++r) {
      int row = q * 4 + r, h = hg * 16 + m;
      float hv = h0[(size_t)(rb + row) * 64 + h];
      float cv = c0[(size_t)(rb + row) * 64 + h];
      ctr[hg * 4 + r] = cv;
      SCR[row * 136 + h] = (unsigned short)bfr(hv);
      SCR[row * 136 + 64 + h] = (unsigned short)bfr(cv);
    }
  lds_fence();

  // ---------- step loop ----------
  float yc[4] = {0.f, 0.f, 0.f, 0.f};
#pragma unroll 1
  for (int s = 0; s < 10; ++s) {
    // A) attn matvec: [ht|ct] @ W1_hc^T (+b1 folded into acc init)
    short8 fa0 = *(const short8*)(SCR + m * 136 + q * 8);
    short8 fa1 = *(const short8*)(SCR + m * 136 + 32 + q * 8);
    short8 fa2 = *(const short8*)(SCR + m * 136 + 64 + q * 8);
    short8 fa3 = *(const short8*)(SCR + m * 136 + 96 + q * 8);
    f32x4 ac4[4];
#pragma unroll
    for (int et = 0; et < 4; ++et) {
      f32x4 acc = {b1e[et], b1e[et], b1e[et], b1e[et]};
      const unsigned short* bp = BHCT + (et * 16 + m) * 136 + q * 8;
      acc = MFMA(fa0, *(const short8*)bp, acc);
      acc = MFMA(fa1, *(const short8*)(bp + 32), acc);
      acc = MFMA(fa2, *(const short8*)(bp + 64), acc);
      acc = MFMA(fa3, *(const short8*)(bp + 96), acc);
      ac4[et] = acc;
    }
    // B/C/D) scores + online (no-max) softmax + context contraction.
    // |score| <= sum|w2| <= 8 -> exp2 args bounded by ~11.5, f32-safe.
    float sm0 = 0.f, sm1 = 0.f, sm2 = 0.f, sm3 = 0.f;
    float cx0 = 0.f, cx1 = 0.f, cx2 = 0.f, cx3 = 0.f;
#pragma unroll
    for (int t = 0; t < 10; ++t) {
      float p0 = 0.f, p1 = 0.f, p2 = 0.f, p3 = 0.f;
#pragma unroll
      for (int et = 0; et < 4; ++et) {
        unsigned plo = ard(ep[t][et][0]), phi = ard(ep[t][et][1]);
        float x0 = ac4[et][0] + ulo(plo);
        float x1 = ac4[et][1] + uhi(plo);
        float x2 = ac4[et][2] + ulo(phi);
        float x3 = ac4[et][3] + uhi(phi);
        // tanh(u) = 1 - 2/(exp2(2u*log2e)+1); args pre-scaled by 2log2e
        float t0 = fmaf(-2.f, __builtin_amdgcn_rcpf(__builtin_amdgcn_exp2f(x0) + 1.f), 1.f);
        float t1 = fmaf(-2.f, __builtin_amdgcn_rcpf(__builtin_amdgcn_exp2f(x1) + 1.f), 1.f);
        float t2 = fmaf(-2.f, __builtin_amdgcn_rcpf(__builtin_amdgcn_exp2f(x2) + 1.f), 1.f);
        float t3 = fmaf(-2.f, __builtin_amdgcn_rcpf(__builtin_amdgcn_exp2f(x3) + 1.f), 1.f);
        float w = w2e[et];
        p0 = fmaf(w, t0, p0); p1 = fmaf(w, t1, p1);
        p2 = fmaf(w, t2, p2); p3 = fmaf(w, t3, p3);
      }
      p0 = sum16(p0); p1 = sum16(p1); p2 = sum16(p2); p3 = sum16(p3);
      float e0 = __builtin_amdgcn_exp2f(p0);
      float e1 = __builtin_amdgcn_exp2f(p1);
      float e2 = __builtin_amdgcn_exp2f(p2);
      float e3 = __builtin_amdgcn_exp2f(p3);
      sm0 += e0; sm1 += e1; sm2 += e2; sm3 += e3;
      unsigned xl = ard(xfo[t][0]), xh = ard(xfo[t][1]);
      cx0 = fmaf(e0, ulo(xl), cx0);
      cx1 = fmaf(e1, uhi(xl), cx1);
      cx2 = fmaf(e2, ulo(xh), cx2);
      cx3 = fmaf(e3, uhi(xh), cx3);
    }
    yc[0] = cx0 * __builtin_amdgcn_rcpf(sm0);
    yc[1] = cx1 * __builtin_amdgcn_rcpf(sm1);
    yc[2] = cx2 * __builtin_amdgcn_rcpf(sm2);
    yc[3] = cx3 * __builtin_amdgcn_rcpf(sm3);
    // E) y_tilde -> YTA (A-layout rows, bf16), lanes m<5 write
#pragma unroll
    for (int r = 0; r < 4; ++r) {
      int row = q * 4 + r;
      float v = yc[r] + fcbv;
#pragma unroll
      for (int j = 0; j < 5; ++j) v += fcwy[j] * YH[row * 50 + s * 5 + j];
      if (m < 5) YTA[row * 40 + m] = (unsigned short)bfr(v);
    }
    lds_fence();
    // F/G) gates = [ht] @ W_hh^T + [y_tilde] @ W_ih^T (+bias in acc init); LSTM update
    short8 ay = *(const short8*)(YTA + m * 40 + q * 8);
#pragma unroll
    for (int hg = 0; hg < 4; ++hg) {
      float ga[4][4];
#pragma unroll
      for (int g = 0; g < 4; ++g) {
        int n = g * 64 + hg * 16 + m;
        float bg = BGC[n];
        f32x4 acc = {bg, bg, bg, bg};
        const unsigned short* bp = BHHT + n * 72 + q * 8;
        acc = MFMA(fa0, *(const short8*)bp, acc);
        acc = MFMA(fa1, *(const short8*)(bp + 32), acc);
        acc = MFMA(ay, *(const short8*)(BIH + n * 40 + q * 8), acc);
        ga[g][0] = acc[0]; ga[g][1] = acc[1]; ga[g][2] = acc[2]; ga[g][3] = acc[3];
      }
#pragma unroll
      for (int r = 0; r < 4; ++r) {
        float iv = __builtin_amdgcn_rcpf(1.f + __builtin_amdgcn_exp2f(ga[0][r]));
        float fv = __builtin_amdgcn_rcpf(1.f + __builtin_amdgcn_exp2f(ga[1][r]));
        float gv = fmaf(-2.f, __builtin_amdgcn_rcpf(__builtin_amdgcn_exp2f(ga[2][r]) + 1.f), 1.f);
        float ov = __builtin_amdgcn_rcpf(1.f + __builtin_amdgcn_exp2f(ga[3][r]));
        float c = fmaf(fv, ctr[hg * 4 + r], iv * gv);
        ctr[hg * 4 + r] = c;
        float th = fmaf(-2.f, __builtin_amdgcn_rcpf(__builtin_amdgcn_exp2f(c * S2) + 1.f), 1.f);
        float hv = ov * th;
        int row = q * 4 + r, h = hg * 16 + m;
        SCR[row * 136 + h] = (unsigned short)bfr(hv);
        SCR[row * 136 + 64 + h] = (unsigned short)bfr(c);
      }
    }
    lds_fence();
  }

  // ---------- output: out = [ht, context] @ fco_w^T + fco_b ----------
#pragma unroll
  for (int r = 0; r < 4; ++r) {
    int row = q * 4 + r;
    float sum = fcobv + __shfl(yc[r], (lane & 48) + 8 + mc);
#pragma unroll
    for (int hq = 0; hq < 8; ++hq) {
      int4v hv = *(const int4v*)(SCR + row * 136 + hq * 8);
      const float* fp = FCOL + mc * 64 + hq * 8;
      sum += fp[0] * ulo((unsigned)hv.x) + fp[1] * uhi((unsigned)hv.x)
           + fp[2] * ulo((unsigned)hv.y) + fp[3] * uhi((unsigned)hv.y)
           + fp[4] * ulo((unsigned)hv.z) + fp[5] * uhi((unsigned)hv.z)
           + fp[6] * ulo((unsigned)hv.w) + fp[7] * uhi((unsigned)hv.w);
    }
    if (m < 5) outg[(size_t)(rb + row) * 5 + m] = sum;
  }
}

extern "C" void kernel_launch(void* const* d_in, const int* in_sizes, int n_in,
                              void* d_out, int out_size, void* d_ws, size_t ws_size,
                              hipStream_t stream) {
  (void)in_sizes; (void)n_in; (void)d_ws; (void)ws_size; (void)out_size;
  (void)hipFuncSetAttribute((const void*)attn_dec,
                            hipFuncAttributeMaxDynamicSharedMemorySize, SMEM_BYTES);
  attn_dec<<<dim3(512), dim3(512), SMEM_BYTES, stream>>>(
      (const float*)d_in[0], (const float*)d_in[1], (const float*)d_in[2],
      (const float*)d_in[3], (const float*)d_in[4], (const float*)d_in[5],
      (const float*)d_in[6], (const float*)d_in[7], (const float*)d_in[8],
      (const float*)d_in[9], (const float*)d_in[10], (const float*)d_in[11],
      (const float*)d_in[12], (const float*)d_in[13], (const float*)d_in[14],
      (const float*)d_in[15], (float*)d_out);
}